// Round 9
// baseline (489.199 us; speedup 1.0000x reference)
//
#include <hip/hip_runtime.h>
#include <math.h>

#define ENV 512
#define NB 128

typedef __attribute__((ext_vector_type(8))) short bf16x8;
typedef __attribute__((ext_vector_type(4))) float f32x4;

// ---------- helpers ----------
__device__ inline float rsum16(float v) {
#pragma unroll
    for (int o = 8; o; o >>= 1) v += __shfl_xor(v, o, 16);
    return v;
}
__device__ inline ushort f2bf(float f) {
    unsigned u = __float_as_uint(f);
    u = u + 0x7fffu + ((u >> 16) & 1u);
    return (ushort)(u >> 16);
}
__device__ inline float bf2f(ushort h) {
    return __uint_as_float(((unsigned)h) << 16);
}

// ---------- weight prep: fp32 [K][C] -> transposed bf16 [C][KP] hi(/lo) ----------
__global__ __launch_bounds__(256) void prep_kernel(
    const float* s0, const float* s1, const float* s2, const float* s3,
    const float* s4, const float* s5, const float* s6, const float* s7,
    const float* s8, const float* s9, const float* s10, const float* s11,
    const float* s12, const float* s13, ushort* wb)
{
    const float* srcs[14] = {s0,s1,s2,s3,s4,s5,s6,s7,s8,s9,s10,s11,s12,s13};
    const int Ks[14]  = {67,64,67,64,67,64, 64,128,64,128,64,128, 128,128};
    const int Cs[14]  = {64,64,64,64,64,64, 128,128,128,128,128,128, 128,128};
    const int KPs[14] = {96,64,96,64,96,64, 64,128,64,128,64,128, 128,128};
    const int offs[14]= {0,12288,20480,32768,40960,53248,
                         61440,77824,110592,126976,159744,176128,
                         208896,225280};
    const int dual[14]= {1,1,1,1,1,1,1,1,1,1,1,1,0,0};
    const int j = blockIdx.x;
    const float* src = srcs[j];
    const int K = Ks[j], C = Cs[j], KP = KPs[j], n = C * KP, d = dual[j];
    ushort* dst = wb + offs[j];
    for (int i = threadIdx.x; i < n; i += 256) {
        int c = i / KP, k = i - c * KP;
        float v = (k < K) ? src[k * C + c] : 0.f;
        ushort h = f2bf(v);
        dst[i] = h;
        if (d) dst[n + i] = f2bf(v - bf2f(h));
    }
}

// ---------- X prep: fp32 [N][67] -> bf16 hi/lo [N][96], zero-padded ----------
__global__ __launch_bounds__(256) void xprep_kernel(
    const float* __restrict__ X, ushort* __restrict__ Xh, ushort* __restrict__ Xl)
{
    const int total = 65536 * 96;
    for (int i = blockIdx.x * 256 + threadIdx.x; i < total; i += gridDim.x * 256) {
        int r = i / 96, k = i - r * 96;
        float v = (k < 67) ? X[(long)r * 67 + k] : 0.f;
        ushort h = f2bf(v);
        Xh[i] = h;
        Xl[i] = f2bf(v - bf2f(h));
    }
}

// ---------- Q&K two-layer MLP, 8 waves, LDS weights ----------
template <int DKP, int DH, int DOUT>
__global__ __launch_bounds__(512, 1) void qk_kernel(
    const ushort* __restrict__ Xg,
    const ushort* __restrict__ Wq1, const float* __restrict__ bq1,
    const ushort* __restrict__ Wq2, const float* __restrict__ bq2,
    const ushort* __restrict__ Wk1, const float* __restrict__ bk1,
    const ushort* __restrict__ Wk2, const float* __restrict__ bk2,
    ushort* __restrict__ Qo, ushort* __restrict__ Ko)
{
    constexpr int KT1 = DKP / 32, CT1 = DH / 16, KT2 = DH / 32, CT2 = DOUT / 16;
    constexpr int W1P = DKP + 8, W2P = DH + 8, HP = DH + 8;
    __shared__ __align__(16) ushort W1s[2][DH * W1P];
    __shared__ __align__(16) ushort W2s[2][DOUT * W2P];
    __shared__ __align__(16) ushort Hs[8][16 * HP];
    const int tid = threadIdx.x, wv = tid >> 6, lid = tid & 63, g = lid >> 4, ln = lid & 15;

    for (int i = tid; i < DH * DKP / 8; i += 512) {
        int c = i / (DKP / 8), j = i - c * (DKP / 8);
        *(uint4*)&W1s[0][c * W1P + j * 8] = *(const uint4*)&Wq1[c * DKP + j * 8];
        *(uint4*)&W1s[1][c * W1P + j * 8] = *(const uint4*)&Wk1[c * DKP + j * 8];
    }
    for (int i = tid; i < DOUT * DH / 8; i += 512) {
        int c = i / (DH / 8), j = i - c * (DH / 8);
        *(uint4*)&W2s[0][c * W2P + j * 8] = *(const uint4*)&Wq2[c * DH + j * 8];
        *(uint4*)&W2s[1][c * W2P + j * 8] = *(const uint4*)&Wk2[c * DH + j * 8];
    }
    __syncthreads();

    const long row0 = (long)blockIdx.x * 128 + wv * 16;
    bf16x8 xa[KT1];
#pragma unroll
    for (int kk = 0; kk < KT1; ++kk)
        xa[kk] = *(const bf16x8*)&Xg[(row0 + ln) * DKP + kk * 32 + 8 * g];

#pragma unroll
    for (int p = 0; p < 2; ++p) {
        const ushort* w1 = W1s[p];
        const ushort* w2 = W2s[p];
        const float* b1 = p ? bk1 : bq1;
        const float* b2 = p ? bk2 : bq2;
        ushort* out = p ? Ko : Qo;
#pragma unroll
        for (int ct = 0; ct < CT1; ++ct) {
            f32x4 a = {0.f, 0.f, 0.f, 0.f};
#pragma unroll
            for (int kk = 0; kk < KT1; ++kk) {
                bf16x8 b = *(const bf16x8*)&w1[(ct * 16 + ln) * W1P + kk * 32 + 8 * g];
                a = __builtin_amdgcn_mfma_f32_16x16x32_bf16(xa[kk], b, a, 0, 0, 0);
            }
            float bb = b1[ct * 16 + ln];
#pragma unroll
            for (int i = 0; i < 4; i++)
                Hs[wv][(4 * g + i) * HP + ct * 16 + ln] = f2bf(fmaxf(a[i] + bb, 0.f));
        }
        bf16x8 ha[KT2];
#pragma unroll
        for (int kk = 0; kk < KT2; ++kk)
            ha[kk] = *(const bf16x8*)&Hs[wv][ln * HP + kk * 32 + 8 * g];
#pragma unroll
        for (int ct = 0; ct < CT2; ++ct) {
            f32x4 a = {0.f, 0.f, 0.f, 0.f};
#pragma unroll
            for (int kk = 0; kk < KT2; ++kk) {
                bf16x8 b = *(const bf16x8*)&w2[(ct * 16 + ln) * W2P + kk * 32 + 8 * g];
                a = __builtin_amdgcn_mfma_f32_16x16x32_bf16(ha[kk], b, a, 0, 0, 0);
            }
            float bb = b2[ct * 16 + ln];
            ushort* op = out + (row0 + 4 * g) * DOUT + ct * 16 + ln;
#pragma unroll
            for (int i = 0; i < 4; i++) op[(long)i * DOUT] = f2bf(a[i] + bb);
        }
    }
}

// ---------- V gemm1: H = relu(X@W1+b1) split-bf16, row-major hi/lo global out ----------
template <int DKP, int DH>
__global__ __launch_bounds__(256, 2) void vg1_kernel(
    const ushort* __restrict__ Xhg, const ushort* __restrict__ Xlg,
    const ushort* __restrict__ Wv1, const float* __restrict__ bv1,
    ushort* __restrict__ Hoh, ushort* __restrict__ Hol)
{
    constexpr int KT1 = DKP / 32, CT1 = DH / 16;
    constexpr int W1P = DKP + 8, HP = DH + 8, sz1 = DH * DKP;
    constexpr int NSEG = DH / 8;
    __shared__ __align__(16) ushort W1s[2][DH * W1P];
    __shared__ __align__(16) ushort Ht[4][2][16 * HP];
    const int tid = threadIdx.x, wv = tid >> 6, lid = tid & 63, g = lid >> 4, ln = lid & 15;

    for (int i = tid; i < DH * DKP / 8; i += 256) {
        int c = i / (DKP / 8), j = i - c * (DKP / 8);
        *(uint4*)&W1s[0][c * W1P + j * 8] = *(const uint4*)&Wv1[c * DKP + j * 8];
        *(uint4*)&W1s[1][c * W1P + j * 8] = *(const uint4*)&Wv1[sz1 + c * DKP + j * 8];
    }
    __syncthreads();

    const long row0 = (long)blockIdx.x * 64 + wv * 16;
    bf16x8 xah[KT1], xal[KT1];
#pragma unroll
    for (int kk = 0; kk < KT1; ++kk) {
        xah[kk] = *(const bf16x8*)&Xhg[(row0 + ln) * DKP + kk * 32 + 8 * g];
        xal[kk] = *(const bf16x8*)&Xlg[(row0 + ln) * DKP + kk * 32 + 8 * g];
    }
#pragma unroll
    for (int ct = 0; ct < CT1; ++ct) {
        f32x4 a0 = {0.f, 0.f, 0.f, 0.f}, a1 = {0.f, 0.f, 0.f, 0.f};
#pragma unroll
        for (int kk = 0; kk < KT1; ++kk) {
            bf16x8 bh = *(const bf16x8*)&W1s[0][(ct * 16 + ln) * W1P + kk * 32 + 8 * g];
            bf16x8 bl = *(const bf16x8*)&W1s[1][(ct * 16 + ln) * W1P + kk * 32 + 8 * g];
            a0 = __builtin_amdgcn_mfma_f32_16x16x32_bf16(xah[kk], bh, a0, 0, 0, 0);
            a1 = __builtin_amdgcn_mfma_f32_16x16x32_bf16(xal[kk], bh, a1, 0, 0, 0);
            a1 = __builtin_amdgcn_mfma_f32_16x16x32_bf16(xah[kk], bl, a1, 0, 0, 0);
        }
        float bb = bv1[ct * 16 + ln];
#pragma unroll
        for (int i = 0; i < 4; i++) {
            float v = fmaxf(a0[i] + a1[i] + bb, 0.f);
            ushort h = f2bf(v);
            int idx = (4 * g + i) * HP + ct * 16 + ln;
            Ht[wv][0][idx] = h;
            Ht[wv][1][idx] = f2bf(v - bf2f(h));
        }
    }
#pragma unroll
    for (int u = 0; u < NSEG / 4; ++u) {
        int i = lid + 64 * u;
        int r = i / NSEG, sg = i - r * NSEG;
        *(uint4*)&Hoh[(row0 + r) * DH + sg * 8] = *(const uint4*)&Ht[wv][0][r * HP + sg * 8];
        *(uint4*)&Hol[(row0 + r) * DH + sg * 8] = *(const uint4*)&Ht[wv][1][r * HP + sg * 8];
    }
}

// ---------- V gemm2: Vt = (H@W2+b2)^T split-bf16, LDS weights ----------
template <int DH, int DOUT>
__global__ __launch_bounds__(256, 2) void vg2_kernel(
    const ushort* __restrict__ Hoh, const ushort* __restrict__ Hol,
    const ushort* __restrict__ Wv2, const float* __restrict__ bv2,
    ushort* __restrict__ Vth, ushort* __restrict__ Vtl)
{
    constexpr int KT2 = DH / 32, CT2 = DOUT / 16;
    constexpr int W2P = DH + 8, sz2 = DOUT * DH;
    __shared__ __align__(16) ushort W2s[2][DOUT * W2P];
    const int tid = threadIdx.x, wv = tid >> 6, lid = tid & 63, g = lid >> 4, ln = lid & 15;

    for (int i = tid; i < DOUT * DH / 8; i += 256) {
        int c = i / (DH / 8), j = i - c * (DH / 8);
        *(uint4*)&W2s[0][c * W2P + j * 8] = *(const uint4*)&Wv2[c * DH + j * 8];
        *(uint4*)&W2s[1][c * W2P + j * 8] = *(const uint4*)&Wv2[sz2 + c * DH + j * 8];
    }
    __syncthreads();

    const long row0 = (long)blockIdx.x * 64 + wv * 16;
    bf16x8 vah[KT2], val[KT2];
#pragma unroll
    for (int kk = 0; kk < KT2; ++kk) {
        vah[kk] = *(const bf16x8*)&Hoh[(row0 + ln) * DH + kk * 32 + 8 * g];
        val[kk] = *(const bf16x8*)&Hol[(row0 + ln) * DH + kk * 32 + 8 * g];
    }
    const int bidx = (int)(row0 >> 9);
    const int e0 = (int)(row0 & 511) + 4 * g;
#pragma unroll
    for (int ct = 0; ct < CT2; ++ct) {
        f32x4 a0 = {0.f, 0.f, 0.f, 0.f}, a1 = {0.f, 0.f, 0.f, 0.f};
#pragma unroll
        for (int kk = 0; kk < KT2; ++kk) {
            bf16x8 bh = *(const bf16x8*)&W2s[0][(ct * 16 + ln) * W2P + kk * 32 + 8 * g];
            bf16x8 bl = *(const bf16x8*)&W2s[1][(ct * 16 + ln) * W2P + kk * 32 + 8 * g];
            a0 = __builtin_amdgcn_mfma_f32_16x16x32_bf16(vah[kk], bh, a0, 0, 0, 0);
            a1 = __builtin_amdgcn_mfma_f32_16x16x32_bf16(val[kk], bh, a1, 0, 0, 0);
            a1 = __builtin_amdgcn_mfma_f32_16x16x32_bf16(vah[kk], bl, a1, 0, 0, 0);
        }
        float bb = bv2[ct * 16 + ln];
        ushort4 hv, lv;
#pragma unroll
        for (int i = 0; i < 4; i++) {
            float v = a0[i] + a1[i] + bb;
            ushort h = f2bf(v);
            ((ushort*)&hv)[i] = h;
            ((ushort*)&lv)[i] = f2bf(v - bf2f(h));
        }
        long o = ((long)bidx * DOUT + ct * 16 + ln) * ENV + e0;
        *(ushort4*)&Vth[o] = hv;
        *(ushort4*)&Vtl[o] = lv;
    }
}

// ---------- MFMA flash attention + fused LayerNorm ----------
// Swapped QK^T: mfma(K,Q) puts each q-row's scores lane-local -> P never
// touches LDS (key-permutation pi(s)= (s&4)? 16+4*(s>>3)+(s&3) : 4*(s>>3)+(s&3)
// applied consistently to P slots and V rows). Max-free softmax; per-lane lsum
// reduced in epilogue via xor-16/32 shuffles. No Ps buffer -> 2 blocks/CU.
template <int D, int OMODE>
__global__ __launch_bounds__(512, 4) void attn_ln_kernel(
    const ushort* __restrict__ Qg, const ushort* __restrict__ Kg,
    const ushort* __restrict__ Vhg, const ushort* __restrict__ Vlg,
    const float* __restrict__ Gw, const float* __restrict__ Bw,
    ushort* __restrict__ Yh, ushort* __restrict__ Yl, float scale)
{
    constexpr int KT = D / 32;
    constexpr int DT = D / 16;
    constexpr int KROW = D + 8;
    constexpr int VROW = 40;
    constexpr int KSEG = D / 8;
    constexpr int KSEGS = 32 * KSEG;
    constexpr int VSEGS = D * 4;
    constexpr int TOTSEG = KSEGS + 2 * VSEGS;
    constexpr int MAXS = (TOTSEG + 511) / 512;
    constexpr int NC = ENV / 32;

    __shared__ __align__(16) ushort Ks[2][32 * KROW];
    __shared__ __align__(16) ushort Vhs[2][D * VROW];
    __shared__ __align__(16) ushort Vls[2][D * VROW];

    const int tid = threadIdx.x;
    const int wv = tid >> 6, lid = tid & 63, g = lid >> 4, ln = lid & 15;

    const int id = blockIdx.x;
    const int xcd = id & 7, rr_ = id >> 3;
    const int b = xcd + 8 * (rr_ >> 1);
    const int q0 = (rr_ & 1) * 256;

    const ushort* Kb  = Kg  + (long)b * ENV * D;
    const ushort* Vhb = Vhg + (long)b * D * ENV;
    const ushort* Vlb = Vlg + (long)b * D * ENV;

    bf16x8 qf[2][KT];
#pragma unroll
    for (int rg = 0; rg < 2; rg++) {
        const ushort* Qrow = Qg + ((long)b * ENV + q0 + wv * 32 + rg * 16 + ln) * D;
#pragma unroll
        for (int kk = 0; kk < KT; kk++)
            qf[rg][kk] = *(const bf16x8*)(Qrow + kk * 32 + 8 * g);
    }

    f32x4 acc[2][DT];
#pragma unroll
    for (int rg = 0; rg < 2; rg++)
#pragma unroll
        for (int dt = 0; dt < DT; dt++) acc[rg][dt] = (f32x4){0.f, 0.f, 0.f, 0.f};
    float lsum[2] = {0.f, 0.f};  // per-lane: q-row = ln

    uint4 stg[MAXS];
    auto LOAD = [&](int c) {
        const int k0 = c * 32;
#pragma unroll
        for (int u = 0; u < MAXS; u++) {
            int s = tid + u * 512;
            if ((TOTSEG % 512 == 0) || s < TOTSEG) {
                const ushort* src;
                if (s < KSEGS) {
                    int row = s / KSEG, sg = s % KSEG;
                    src = Kb + (long)(k0 + row) * D + sg * 8;
                } else {
                    int s2 = s - KSEGS;
                    const ushort* Vb = (s2 < VSEGS) ? Vhb : Vlb;
                    int s3 = (s2 < VSEGS) ? s2 : s2 - VSEGS;
                    int d = s3 >> 2, sg = s3 & 3;
                    src = Vb + (long)d * ENV + k0 + sg * 8;
                }
                stg[u] = *(const uint4*)src;
            }
        }
    };
    auto WRITE = [&](int buf) {
#pragma unroll
        for (int u = 0; u < MAXS; u++) {
            int s = tid + u * 512;
            if ((TOTSEG % 512 == 0) || s < TOTSEG) {
                ushort* dst;
                if (s < KSEGS) {
                    int row = s / KSEG, sg = s % KSEG;
                    dst = &Ks[buf][row * KROW + sg * 8];
                } else {
                    int s2 = s - KSEGS;
                    ushort* Vb = (s2 < VSEGS) ? &Vhs[buf][0] : &Vls[buf][0];
                    int s3 = (s2 < VSEGS) ? s2 : s2 - VSEGS;
                    int d = s3 >> 2, sg = s3 & 3;
                    dst = Vb + d * VROW + sg * 8;
                }
                *(uint4*)dst = stg[u];
            }
        }
    };

    LOAD(0);
    WRITE(0);
    __syncthreads();

    for (int c = 0; c < NC; c++) {
        const int cur = c & 1;
        if (c + 1 < NC) LOAD(c + 1);

        // swapped QK^T: sacc[rg][t] elem i = score(q row ln, key 16t+4g+i)
        f32x4 sacc[2][2];
#pragma unroll
        for (int rg = 0; rg < 2; rg++)
#pragma unroll
            for (int t = 0; t < 2; t++) sacc[rg][t] = (f32x4){0.f, 0.f, 0.f, 0.f};
#pragma unroll
        for (int t = 0; t < 2; t++)
#pragma unroll
            for (int kk = 0; kk < KT; kk++) {
                bf16x8 kf = *(const bf16x8*)&Ks[cur][(16 * t + ln) * KROW + kk * 32 + 8 * g];
#pragma unroll
                for (int rg = 0; rg < 2; rg++)
                    sacc[rg][t] = __builtin_amdgcn_mfma_f32_16x16x32_bf16(kf, qf[rg][kk], sacc[rg][t], 0, 0, 0);
            }

        // exp + in-register split P fragments (slot j<4 -> t=0 i=j; j>=4 -> t=1 i=j-4)
        bf16x8 phi[2], plo[2];
#pragma unroll
        for (int rg = 0; rg < 2; rg++) {
            float ls = 0.f;
#pragma unroll
            for (int j = 0; j < 8; j++) {
                float s = (j < 4) ? sacc[rg][0][j] : sacc[rg][1][j - 4];
                float p = __expf(fminf(s * scale, 50.f));
                ls += p;
                ushort h = f2bf(p);
                phi[rg][j] = (short)h;
                plo[rg][j] = (short)f2bf(p - bf2f(h));
            }
            lsum[rg] += ls;
        }

        // PV: B-fragment = V rows at permuted positions {4g..4g+3, 16+4g..16+4g+3}
#pragma unroll
        for (int dt = 0; dt < DT; dt++) {
            const ushort* vrh = &Vhs[cur][(dt * 16 + ln) * VROW];
            const ushort* vrl = &Vls[cur][(dt * 16 + ln) * VROW];
            ushort4 ha = *(const ushort4*)(vrh + 4 * g);
            ushort4 hb = *(const ushort4*)(vrh + 16 + 4 * g);
            ushort4 la = *(const ushort4*)(vrl + 4 * g);
            ushort4 lb = *(const ushort4*)(vrl + 16 + 4 * g);
            bf16x8 vh, vl;
            vh[0] = (short)ha.x; vh[1] = (short)ha.y; vh[2] = (short)ha.z; vh[3] = (short)ha.w;
            vh[4] = (short)hb.x; vh[5] = (short)hb.y; vh[6] = (short)hb.z; vh[7] = (short)hb.w;
            vl[0] = (short)la.x; vl[1] = (short)la.y; vl[2] = (short)la.z; vl[3] = (short)la.w;
            vl[4] = (short)lb.x; vl[5] = (short)lb.y; vl[6] = (short)lb.z; vl[7] = (short)lb.w;
#pragma unroll
            for (int rg = 0; rg < 2; rg++) {
                acc[rg][dt] = __builtin_amdgcn_mfma_f32_16x16x32_bf16(phi[rg], vh, acc[rg][dt], 0, 0, 0);
                acc[rg][dt] = __builtin_amdgcn_mfma_f32_16x16x32_bf16(plo[rg], vh, acc[rg][dt], 0, 0, 0);
                acc[rg][dt] = __builtin_amdgcn_mfma_f32_16x16x32_bf16(phi[rg], vl, acc[rg][dt], 0, 0, 0);
            }
        }

        if (c + 1 < NC) WRITE(cur ^ 1);
        __syncthreads();
    }

    // reduce lsum (q-row ln) across the 4 g-groups
    float lr[2];
#pragma unroll
    for (int rg = 0; rg < 2; rg++) {
        float v = lsum[rg];
        v += __shfl_xor(v, 16);
        v += __shfl_xor(v, 32);
        lr[rg] = v;
    }

    // epilogue: 1/l + LayerNorm + bf16 store (acc layout: row 4g+i, col ln)
    float gg[DT], bb[DT];
#pragma unroll
    for (int dt = 0; dt < DT; dt++) {
        gg[dt] = Gw[dt * 16 + ln];
        bb[dt] = Bw[dt * 16 + ln];
    }
#pragma unroll
    for (int rg = 0; rg < 2; rg++) {
        const long base = ((long)b * ENV + q0 + wv * 32 + rg * 16 + 4 * g) * D + ln;
#pragma unroll
        for (int i = 0; i < 4; i++) {
            float l = __shfl(lr[rg], 4 * g + i, 16);
            float inv = 1.f / l;
            float o[DT], s1 = 0.f, s2 = 0.f;
#pragma unroll
            for (int dt = 0; dt < DT; dt++) {
                o[dt] = acc[rg][dt][i] * inv;
                s1 += o[dt];
                s2 += o[dt] * o[dt];
            }
            s1 = rsum16(s1);
            s2 = rsum16(s2);
            float mean = s1 / D;
            float var = s2 / D - mean * mean;
            float rstd = rsqrtf(var + 1e-5f);
#pragma unroll
            for (int dt = 0; dt < DT; dt++) {
                float y = (o[dt] - mean) * rstd * gg[dt] + bb[dt];
                long idx = base + (long)i * D + dt * 16;
                ushort h = f2bf(y);
                Yh[idx] = h;
                if constexpr (OMODE == 1) Yl[idx] = f2bf(y - bf2f(h));
            }
        }
    }
}

// ---------- aggregator ----------
__global__ __launch_bounds__(256, 1) void agg_h_kernel(
    const ushort* __restrict__ X2b, const ushort* __restrict__ W1t,
    const float* __restrict__ b1, const float* __restrict__ wsv,
    ushort* __restrict__ H, float* __restrict__ logits)
{
    __shared__ __align__(16) ushort W1s[128 * 136];
    const int tid = threadIdx.x;
    const int wv = tid >> 6, lid = tid & 63, g = lid >> 4, ln = lid & 15;
    const long row0 = (long)blockIdx.x * 64;

    for (int i = tid; i < 128 * 16; i += 256) {
        int c = i >> 4, j = i & 15;
        *(uint4*)&W1s[c * 136 + j * 8] = *(const uint4*)&W1t[c * 128 + j * 8];
    }
    __syncthreads();

    bf16x8 ah[4];
#pragma unroll
    for (int kk = 0; kk < 4; kk++)
        ah[kk] = *(const bf16x8*)&X2b[(row0 + wv * 16 + ln) * 128 + kk * 32 + 8 * g];

    float part[4] = {0.f, 0.f, 0.f, 0.f};
#pragma unroll
    for (int ct = 0; ct < 8; ct++) {
        f32x4 a = {0.f, 0.f, 0.f, 0.f};
#pragma unroll
        for (int kk = 0; kk < 4; kk++) {
            bf16x8 bh = *(const bf16x8*)&W1s[(ct * 16 + ln) * 136 + kk * 32 + 8 * g];
            a = __builtin_amdgcn_mfma_f32_16x16x32_bf16(ah[kk], bh, a, 0, 0, 0);
        }
        float bb = b1[ct * 16 + ln], wc = wsv[ct * 16 + ln];
        ushort* hp = H + (row0 + wv * 16 + 4 * g) * 128 + ct * 16 + ln;
#pragma unroll
        for (int i = 0; i < 4; i++) {
            float v = fmaxf(a[i] + bb, 0.f);
            hp[(long)i * 128] = f2bf(v);
            part[i] += v * wc;
        }
    }
#pragma unroll
    for (int i = 0; i < 4; i++) {
        float s = rsum16(part[i]);
        if (ln == 0) logits[row0 + wv * 16 + 4 * g + i] = s;
    }
}

__global__ __launch_bounds__(256) void agg_pool_kernel(
    const ushort* __restrict__ H, const float* __restrict__ logits,
    const float* __restrict__ W2, const float* __restrict__ b2,
    float* __restrict__ bias2b)
{
    __shared__ float es[ENV];
    __shared__ float sred[4];
    __shared__ float pl[2][128];
    const int b = blockIdx.x, tid = threadIdx.x;
    const float* lg = logits + (long)b * ENV;

    float lm = -1e30f;
    for (int i = tid; i < ENV; i += 256) lm = fmaxf(lm, lg[i]);
#pragma unroll
    for (int o = 32; o; o >>= 1) lm = fmaxf(lm, __shfl_xor(lm, o, 64));
    if ((tid & 63) == 0) sred[tid >> 6] = lm;
    __syncthreads();
    float M = fmaxf(fmaxf(sred[0], sred[1]), fmaxf(sred[2], sred[3]));

    float ls = 0.f;
    for (int i = tid; i < ENV; i += 256) {
        float e = __expf(lg[i] - M);
        es[i] = e;
        ls += e;
    }
#pragma unroll
    for (int o = 32; o; o >>= 1) ls += __shfl_xor(ls, o, 64);
    __syncthreads();
    if ((tid & 63) == 0) sred[tid >> 6] = ls;
    __syncthreads();
    float S = sred[0] + sred[1] + sred[2] + sred[3];
    float inv = 1.f / S;

    int half = tid >> 7, c = tid & 127;
    float acc = 0.f;
    const ushort* Hb = H + (long)b * ENV * 128;
    for (int rr = half * 256; rr < half * 256 + 256; rr++)
        acc += es[rr] * bf2f(Hb[rr * 128 + c]);
    pl[half][c] = acc;
    __syncthreads();
    if (tid < 128) pl[0][tid] = (pl[0][tid] + pl[1][tid]) * inv;
    __syncthreads();
    if (tid < 128) {
        float a = b2[tid];
        for (int k = 0; k < 128; k++) a += pl[0][k] * W2[k * 128 + tid];
        bias2b[(long)b * 128 + tid] = a;
    }
}

__global__ __launch_bounds__(256, 1) void agg_out_kernel(
    const ushort* __restrict__ H, const ushort* __restrict__ W2t,
    const float* __restrict__ bias2b, float* __restrict__ out)
{
    __shared__ __align__(16) ushort W2s[128 * 136];
    const int tid = threadIdx.x;
    const int wv = tid >> 6, lid = tid & 63, g = lid >> 4, ln = lid & 15;
    const long row0 = (long)blockIdx.x * 64;
    const int b = (int)(row0 >> 9);

    for (int i = tid; i < 128 * 16; i += 256) {
        int c = i >> 4, j = i & 15;
        *(uint4*)&W2s[c * 136 + j * 8] = *(const uint4*)&W2t[c * 128 + j * 8];
    }
    __syncthreads();

    bf16x8 ah[4];
#pragma unroll
    for (int kk = 0; kk < 4; kk++)
        ah[kk] = *(const bf16x8*)&H[(row0 + wv * 16 + ln) * 128 + kk * 32 + 8 * g];

    const float* bb2 = bias2b + (long)b * 128;
#pragma unroll
    for (int ct = 0; ct < 8; ct++) {
        f32x4 a = {0.f, 0.f, 0.f, 0.f};
#pragma unroll
        for (int kk = 0; kk < 4; kk++) {
            bf16x8 bh = *(const bf16x8*)&W2s[(ct * 16 + ln) * 136 + kk * 32 + 8 * g];
            a = __builtin_amdgcn_mfma_f32_16x16x32_bf16(ah[kk], bh, a, 0, 0, 0);
        }
        float bb = bb2[ct * 16 + ln];
        float* op = out + (row0 + wv * 16 + 4 * g) * 128 + ct * 16 + ln;
#pragma unroll
        for (int i = 0; i < 4; i++) op[(long)i * 128] = a[i] + bb;
    }
}

extern "C" void kernel_launch(void* const* d_in, const int* in_sizes, int n_in,
                              void* d_out, int out_size, void* d_ws, size_t ws_size,
                              hipStream_t stream)
{
    const float* X = (const float*)d_in[0];
    const float* g1  = (const float*)d_in[25];
    const float* be1 = (const float*)d_in[26];
    const float* g2  = (const float*)d_in[27];
    const float* be2 = (const float*)d_in[28];

    ushort* U = (ushort*)d_ws;
    const long S1 = (long)NB * ENV * 64;    // 4,194,304
    const long S2 = (long)NB * ENV * 128;   // 8,388,608
    const long N  = (long)NB * ENV;
    const long XS = N * 96;                 // 6,291,456

    // R0 [0, 2*XS): XP -> V1 -> K2
    ushort* XPh = U;          ushort* XPl = U + XS;
    ushort* V1h = U;          ushort* V1l = U + S1;
    ushort* K2  = U;
    // R1 [2*XS, 2*XS+S2): Q1,K1 -> Q2
    ushort* Q1 = U + 2 * XS;  ushort* K1 = Q1 + S1;
    ushort* Q2 = U + 2 * XS;
    // R2 [2*XS+S2, 2*XS+2*S2): Hv1 -> X1 -> V2h
    ushort* Hv1h = U + 2 * XS + S2;  ushort* Hv1l = Hv1h + S1;
    ushort* X1h  = Hv1h;             ushort* X1l  = Hv1l;
    ushort* V2h  = Hv1h;
    // R3 [2*XS+2*S2, 2*XS+4*S2): Hv2 -> X2b,Hb
    ushort* Hv2h = U + 2 * XS + 2 * S2;  ushort* Hv2l = Hv2h + S2;
    ushort* X2b  = Hv2h;                 ushort* Hb   = Hv2l;
    // R4 [2*XS+4*S2, 2*XS+5*S2): V2l
    ushort* V2l = U + 2 * XS + 4 * S2;
    // tail
    float*  logits = (float*)(U + 2 * XS + 5 * S2);
    float*  bias2b = logits + N;
    ushort* wb = (ushort*)(bias2b + (long)NB * 128);

    const ushort *L1q1 = wb + 0,      *L1q2 = wb + 12288,
                 *L1k1 = wb + 20480,  *L1k2 = wb + 32768,
                 *L1v1 = wb + 40960,  *L1v2 = wb + 53248,
                 *L2q1 = wb + 61440,  *L2q2 = wb + 77824,
                 *L2k1 = wb + 110592, *L2k2 = wb + 126976,
                 *L2v1 = wb + 159744, *L2v2 = wb + 176128,
                 *AW1  = wb + 208896, *AW2  = wb + 225280;

    dim3 blk(256);

    prep_kernel<<<14, blk, 0, stream>>>(
        (const float*)d_in[1], (const float*)d_in[3], (const float*)d_in[5],
        (const float*)d_in[7], (const float*)d_in[9], (const float*)d_in[11],
        (const float*)d_in[13], (const float*)d_in[15], (const float*)d_in[17],
        (const float*)d_in[19], (const float*)d_in[21], (const float*)d_in[23],
        (const float*)d_in[29], (const float*)d_in[32], wb);
    xprep_kernel<<<6144, blk, 0, stream>>>(X, XPh, XPl);

    // layer 1
    qk_kernel<96, 64, 64><<<512, dim3(512), 0, stream>>>(
        XPh, L1q1, (const float*)d_in[2], L1q2, (const float*)d_in[4],
        L1k1, (const float*)d_in[6], L1k2, (const float*)d_in[8], Q1, K1);
    vg1_kernel<96, 64><<<1024, blk, 0, stream>>>(
        XPh, XPl, L1v1, (const float*)d_in[10], Hv1h, Hv1l);
    vg2_kernel<64, 64><<<1024, blk, 0, stream>>>(
        Hv1h, Hv1l, L1v2, (const float*)d_in[12], V1h, V1l);
    attn_ln_kernel<64, 1><<<dim3(256), dim3(512), 0, stream>>>(
        Q1, K1, V1h, V1l, g1, be1, X1h, X1l, 0.125f);

    // layer 2
    qk_kernel<64, 128, 128><<<512, dim3(512), 0, stream>>>(
        X1h, L2q1, (const float*)d_in[14], L2q2, (const float*)d_in[16],
        L2k1, (const float*)d_in[18], L2k2, (const float*)d_in[20], Q2, K2);
    vg1_kernel<64, 128><<<1024, blk, 0, stream>>>(
        X1h, X1l, L2v1, (const float*)d_in[22], Hv2h, Hv2l);
    vg2_kernel<128, 128><<<1024, blk, 0, stream>>>(
        Hv2h, Hv2l, L2v2, (const float*)d_in[24], V2h, V2l);
    attn_ln_kernel<128, 2><<<dim3(256), dim3(512), 0, stream>>>(
        Q2, K2, V2h, V2l, g2, be2, X2b, nullptr, 0.08838834764831845f);

    // aggregator
    agg_h_kernel<<<1024, blk, 0, stream>>>(
        X2b, AW1, (const float*)d_in[30], (const float*)d_in[31], Hb, logits);
    agg_pool_kernel<<<NB, blk, 0, stream>>>(
        Hb, logits, (const float*)d_in[32], (const float*)d_in[33], bias2b);
    agg_out_kernel<<<1024, blk, 0, stream>>>(
        Hb, AW2, bias2b, (float*)d_out);
}